// Round 8
// baseline (649.464 us; speedup 1.0000x reference)
//
#include <hip/hip_runtime.h>
#include <cstdint>
#include <cstddef>

typedef __bf16 bf16x8 __attribute__((ext_vector_type(8)));
typedef float  f32x4  __attribute__((ext_vector_type(4)));

#define S_TXT 256
#define S_IMG 2048
#define S_TOT 2304
#define NHEAD 24
#define HDIM  128
#define DMODEL 3072

static constexpr size_t SZ_QKV  = (size_t)NHEAD * S_TOT * HDIM;
static constexpr size_t SZ_AO   = (size_t)S_TOT * DMODEL;
static constexpr size_t SZ_XIMG = (size_t)S_IMG * DMODEL;
static constexpr size_t SZ_XTXT = (size_t)S_TXT * DMODEL;

__device__ __forceinline__ f32x4 mfma16(bf16x8 a, bf16x8 b, f32x4 c) {
  return __builtin_amdgcn_mfma_f32_16x16x32_bf16(a, b, c, 0, 0, 0);
}

// ---------------- fp32 -> bf16 convert (RNE) ----------------
__global__ __launch_bounds__(256) void cvt_f32_bf16(const float* __restrict__ in,
                                                    __bf16* __restrict__ out, int n) {
  int i = (blockIdx.x * 256 + threadIdx.x) * 8;
  if (i + 8 > n) return;
  f32x4 a = *(const f32x4*)(in + i);
  f32x4 b = *(const f32x4*)(in + i + 4);
  bf16x8 r;
  r[0]=(__bf16)a[0]; r[1]=(__bf16)a[1]; r[2]=(__bf16)a[2]; r[3]=(__bf16)a[3];
  r[4]=(__bf16)b[0]; r[5]=(__bf16)b[1]; r[6]=(__bf16)b[2]; r[7]=(__bf16)b[3];
  *(bf16x8*)(out + i) = r;
}

// ---------------- RoPE in-place; Q additionally pre-scaled by 1/sqrt(HD) ----------------
__global__ __launch_bounds__(256) void rope_kernel(__bf16* __restrict__ Qb, __bf16* __restrict__ Kb,
    const float* __restrict__ icos, const float* __restrict__ isin,
    const float* __restrict__ tcos, const float* __restrict__ tsin) {
  size_t idx = ((size_t)blockIdx.x * 256 + threadIdx.x) * 8;
  __bf16* X; float mult;
  if (blockIdx.y) { X = Kb; mult = 1.0f; }
  else            { X = Qb; mult = 0.08838834764831845f; }
  int d = (int)(idx & 127);
  int s = (int)((idx >> 7) % S_TOT);
  const float *cp, *sp; int ss;
  if (s < S_TXT) { cp = tcos; sp = tsin; ss = s; }
  else           { cp = icos; sp = isin; ss = s - S_TXT; }
  const float* cb = cp + (size_t)ss * HDIM + d;
  const float* sb = sp + (size_t)ss * HDIM + d;
  f32x4 c0 = *(const f32x4*)(cb);
  f32x4 c1 = *(const f32x4*)(cb + 4);
  f32x4 s0 = *(const f32x4*)(sb);
  f32x4 s1 = *(const f32x4*)(sb + 4);
  bf16x8 x = *(const bf16x8*)(X + idx);
  float xf[8];
  #pragma unroll
  for (int j = 0; j < 8; ++j) xf[j] = (float)x[j];
  bf16x8 o;
  o[0] = (__bf16)((xf[0]*c0[0] - xf[1]*s0[0]) * mult);
  o[1] = (__bf16)((xf[1]*c0[1] + xf[0]*s0[1]) * mult);
  o[2] = (__bf16)((xf[2]*c0[2] - xf[3]*s0[2]) * mult);
  o[3] = (__bf16)((xf[3]*c0[3] + xf[2]*s0[3]) * mult);
  o[4] = (__bf16)((xf[4]*c1[0] - xf[5]*s1[0]) * mult);
  o[5] = (__bf16)((xf[5]*c1[1] + xf[4]*s1[1]) * mult);
  o[6] = (__bf16)((xf[6]*c1[2] - xf[7]*s1[2]) * mult);
  o[7] = (__bf16)((xf[7]*c1[3] + xf[6]*s1[3]) * mult);
  *(bf16x8*)(X + idx) = o;
}

// ---------------- V [h][s][d] -> Vt [h][d][s] ----------------
__global__ __launch_bounds__(128) void transpose_v(const __bf16* __restrict__ V,
                                                   __bf16* __restrict__ Vt) {
  int h = blockIdx.y, s0 = blockIdx.x * 64, d = threadIdx.x;
  const __bf16* src = V + ((size_t)h * S_TOT + s0) * HDIM + d;
  __bf16 tmp[64];
  #pragma unroll
  for (int k = 0; k < 64; ++k) tmp[k] = src[(size_t)k * HDIM];
  __bf16* dst = Vt + ((size_t)h * HDIM + d) * S_TOT + s0;
  #pragma unroll
  for (int k = 0; k < 8; ++k) {
    bf16x8 v;
    #pragma unroll
    for (int j = 0; j < 8; ++j) v[j] = tmp[k*8 + j];
    *(bf16x8*)(dst + k*8) = v;
  }
}

// ---------------- fused GEMM, BM=128 x BN=128, BK=64 ----------------
// Latency-bound fix (r8): keep the counted-vmcnt A-dbuf pipeline but shrink
// the tile so 3 blocks/CU co-reside (48KB LDS, VGPR<=170 via bounds(256,3)).
// A: LDS double-buffered via global_load_lds (2x16KB). W (fp32): 2-deep reg
// prefetch + cvt + swizzled ds_write into single 16KB Bs.
// vmcnt ledger (per-thread ops: ISSUE_A=4, ISSUE_B=8):
//   steady iter t: [B[t+1](8)] +A(4)+B(8) -> vmcnt(12) drains B[t+1] ->
//   COMPUTE -> barrier -> WRITE_B -> vmcnt(8) drains A[t+1], keeps B[t+2] -> barrier
struct GArgs {
  const __bf16* A;
  const float* W0[3]; const float* W1[3];
  const float* b0[3]; const float* b1[3];
  void* O0[3]; void* O1[3];
};

#define NT 48   // 3072/64

template<int MODE>
__global__ __launch_bounds__(256, 3) void gemm_all(GArgs ga) {
  const int tid = threadIdx.x;
  const int lane = tid & 63, wave = tid >> 6;
  const int wr = wave >> 1, wc = wave & 1;
  const int g = lane >> 4, lr = lane & 15;
  const int x7 = lr & 7;

  // 1296 = 8 XCD x (9 n-rows x 18 m-tiles), m-fastest (MODE 0)
  //  432 = 8 XCD x (3 n-rows x 18 m-tiles)             (MODE 1)
  const int hw = (int)blockIdx.x;
  const int xcd = hw & 7, idx = hw >> 3;
  const int bx = idx % 18;
  const int nglob = (MODE == 0) ? (xcd * 9 + idx / 18) : (xcd * 3 + idx / 18);
  const int wsel = (MODE == 0) ? nglob / 24 : 0;
  const int ny   = (MODE == 0) ? nglob % 24 : nglob;
  const int m0 = bx * 128;
  const int n0 = ny * 128;
  const bool txt = (MODE == 0) ? (m0 >= S_IMG) : (m0 < S_TXT);
  const float* Wf   = txt ? ga.W1[wsel] : ga.W0[wsel];
  const float* bias = txt ? ga.b1[wsel] : ga.b0[wsel];

  __shared__ __align__(16) __bf16 As[2][128 * 64];   // 2 x 16 KB
  __shared__ __align__(16) __bf16 Bs[128 * 64];      // 16 KB  (48 KB total)

  // A staging: issue i covers rows [i*32,+32); thread -> row i*32 + wave*8 + (l>>3),
  // phys slot l&7; logical chunk (l&7)^(row&7) pre-swizzled on the global side.
  const int sr8 = lane >> 3;
  const int sch = (lane & 7) ^ sr8;
  const __bf16* Ap = ga.A + (size_t)(m0 + wave * 8 + sr8) * DMODEL + sch * 8;

  // W staging: pass p: row p*32 + (tid>>3), fp32 chunk tid&7; swizzled ds_write.
  const int wrow = tid >> 3;
  const int wch  = tid & 7;
  const float* Bp = Wf + (size_t)(n0 + wrow) * DMODEL + wch * 8;
  const int bwoff = wrow * 128 + ((wch ^ (wrow & 7)) << 4);

  f32x4 acc[4][4];
  #pragma unroll
  for (int i = 0; i < 4; ++i)
    #pragma unroll
    for (int j = 0; j < 4; ++j) acc[i][j] = (f32x4){0.f,0.f,0.f,0.f};

  f32x4 pre0[4][2], pre1[4][2];

#define VSEP asm volatile("" ::: "memory")

#define ISSUE_A(kt, buf) { \
    const __bf16* Apk = Ap + (kt) * 64; \
    char* dst = (char*)(&As[(buf)][0]) + wave * 1024; \
    _Pragma("unroll") \
    for (int i_ = 0; i_ < 4; ++i_) \
      __builtin_amdgcn_global_load_lds( \
          (const __attribute__((address_space(1))) void*)(Apk + (size_t)i_ * 32 * DMODEL), \
          (__attribute__((address_space(3))) void*)(dst + i_ * 4096), 16, 0, 0); }

#define ISSUE_B(kt, PRE) { \
    const float* Bpk = Bp + (kt) * 64; \
    _Pragma("unroll") \
    for (int p_ = 0; p_ < 4; ++p_) { \
      PRE[p_][0] = *(const f32x4*)(Bpk + (size_t)p_ * 32 * DMODEL); \
      PRE[p_][1] = *(const f32x4*)(Bpk + (size_t)p_ * 32 * DMODEL + 4); } }

#define WRITE_B(PRE) { \
    _Pragma("unroll") \
    for (int p_ = 0; p_ < 4; ++p_) { \
      bf16x8 bw_; \
      _Pragma("unroll") \
      for (int j_ = 0; j_ < 4; ++j_) { \
        bw_[j_]     = (__bf16)PRE[p_][0][j_]; \
        bw_[4 + j_] = (__bf16)PRE[p_][1][j_]; } \
      *(bf16x8*)((char*)Bs + p_ * 4096 + bwoff) = bw_; } }

#define COMPUTE(buf) { \
    _Pragma("unroll") \
    for (int ks_ = 0; ks_ < 2; ++ks_) { \
      bf16x8 af_[4], bf_[4]; \
      _Pragma("unroll") \
      for (int i_ = 0; i_ < 4; ++i_) \
        af_[i_] = *(const bf16x8*)((char*)(&As[(buf)][0]) + (wr*64 + i_*16 + lr) * 128 + (((ks_*4 + g) ^ x7) << 4)); \
      _Pragma("unroll") \
      for (int j_ = 0; j_ < 4; ++j_) \
        bf_[j_] = *(const bf16x8*)((char*)Bs + (wc*64 + j_*16 + lr) * 128 + (((ks_*4 + g) ^ x7) << 4)); \
      __builtin_amdgcn_s_setprio(1); \
      _Pragma("unroll") \
      for (int i_ = 0; i_ < 4; ++i_) \
        _Pragma("unroll") \
        for (int j_ = 0; j_ < 4; ++j_) \
          acc[i_][j_] = mfma16(af_[i_], bf_[j_], acc[i_][j_]); \
      __builtin_amdgcn_s_setprio(0); } }

  // ---- prologue: Bs <- tile0, As[0] <- tile0, B[1] in regs ----
  ISSUE_B(0, pre0);  VSEP;
  ISSUE_A(0, 0);     VSEP;
  ISSUE_B(1, pre1);
  asm volatile("s_waitcnt vmcnt(12)" ::: "memory");   // B[0] regs ready
  WRITE_B(pre0);
  asm volatile("s_waitcnt vmcnt(8) lgkmcnt(0)" ::: "memory");  // A[0] resident; B[1] in flight
  __builtin_amdgcn_s_barrier();
  VSEP;

  // ---- main loop: iters 0..45 as 23 unrolled pairs ----
  for (int t = 0; t < NT - 2; t += 2) {
    // even iter t: compute As[0]/tile t
    ISSUE_A(t + 1, 1);  VSEP;
    ISSUE_B(t + 2, pre0);
    asm volatile("s_waitcnt vmcnt(12)" ::: "memory");  // B[t+1] regs ready
    COMPUTE(0);
    __builtin_amdgcn_s_barrier();                      // all waves done reading Bs
    WRITE_B(pre1);
    asm volatile("s_waitcnt vmcnt(8) lgkmcnt(0)" ::: "memory");  // A[t+1] resident; B[t+2] stays
    __builtin_amdgcn_s_barrier();
    VSEP;
    // odd iter t+1: compute As[1]/tile t+1
    ISSUE_A(t + 2, 0);  VSEP;
    ISSUE_B(t + 3, pre1);
    asm volatile("s_waitcnt vmcnt(12)" ::: "memory");  // B[t+2] regs ready
    COMPUTE(1);
    __builtin_amdgcn_s_barrier();
    WRITE_B(pre0);
    asm volatile("s_waitcnt vmcnt(8) lgkmcnt(0)" ::: "memory");  // A[t+2] resident; B[t+3] stays
    __builtin_amdgcn_s_barrier();
    VSEP;
  }

  // ---- peeled iter 46 (tile 46 in As[0], B[47] regs arriving in pre1) ----
  ISSUE_A(NT - 1, 1);
  asm volatile("s_waitcnt vmcnt(4)" ::: "memory");     // B[47] regs ready (A[47] in flight)
  COMPUTE(0);
  __builtin_amdgcn_s_barrier();
  WRITE_B(pre1);
  asm volatile("s_waitcnt vmcnt(0) lgkmcnt(0)" ::: "memory");
  __builtin_amdgcn_s_barrier();
  // ---- peeled iter 47 ----
  COMPUTE(1);

#undef VSEP
#undef ISSUE_A
#undef ISSUE_B
#undef WRITE_B
#undef COMPUTE

  float bv[4];
  #pragma unroll
  for (int j = 0; j < 4; ++j) bv[j] = bias[n0 + wc*64 + j*16 + lr];

  if (MODE == 0) {
    __bf16* Qp = (__bf16*)(txt ? ga.O1[wsel] : ga.O0[wsel]);
    const int sbase = txt ? (m0 - S_IMG) : (m0 + S_TXT);
    #pragma unroll
    for (int i = 0; i < 4; ++i)
      #pragma unroll
      for (int j = 0; j < 4; ++j)
        #pragma unroll
        for (int r = 0; r < 4; ++r) {
          int s  = sbase + wr*64 + i*16 + g*4 + r;
          int hd = wc*64 + j*16 + lr;
          Qp[((size_t)ny * S_TOT + s) * HDIM + hd] = (__bf16)(acc[i][j][r] + bv[j]);
        }
  } else {
    float* Cf = (float*)(txt ? ga.O1[0] : ga.O0[0]);
    const int rbase = txt ? m0 : (m0 - S_TXT);
    #pragma unroll
    for (int i = 0; i < 4; ++i)
      #pragma unroll
      for (int j = 0; j < 4; ++j)
        #pragma unroll
        for (int r = 0; r < 4; ++r) {
          int m = rbase + wr*64 + i*16 + g*4 + r;
          int n = n0 + wc*64 + j*16 + lr;
          Cf[(size_t)m * DMODEL + n] = acc[i][j][r] + bv[j];
        }
  }
}

// ---------------- flash attention (r4 structure, unchanged) ----------------
__global__ __launch_bounds__(256, 3) void flash_attn(
    const __bf16* __restrict__ Qg, const __bf16* __restrict__ Kg,
    const __bf16* __restrict__ Vt, __bf16* __restrict__ Og)
{
  const int h = blockIdx.y;
  const int q0 = blockIdx.x * 64;
  const int tid = threadIdx.x;
  const int lane = tid & 63, wave = tid >> 6;
  const int g = lane >> 4, lr = lane & 15;
  const int x7 = lr & 7;

  __shared__ __align__(16) __bf16 Kl[64 * 128];    // [kv][d]   256B rows
  __shared__ __align__(16) __bf16 Vl[128 * 64];    // [d][kv]   128B rows
  __shared__ __align__(16) __bf16 Pl[4][16 * 64];  // per-wave [q][kv] 128B rows
  char* Kc = (char*)Kl;
  char* Vc = (char*)Vl;
  char* Pc = (char*)&Pl[wave][0];

  bf16x8 qf[4];
  {
    const __bf16* qp = Qg + ((size_t)h * S_TOT + q0 + wave*16 + lr) * HDIM + g * 8;
    #pragma unroll
    for (int kb = 0; kb < 4; ++kb) qf[kb] = *(const bf16x8*)(qp + kb * 32);
  }

  f32x4 acc[8];
  #pragma unroll
  for (int i = 0; i < 8; ++i) acc[i] = (f32x4){0.f,0.f,0.f,0.f};
  float mrow[4] = {-__builtin_inff(), -__builtin_inff(), -__builtin_inff(), -__builtin_inff()};
  float lrow[4] = {0.f, 0.f, 0.f, 0.f};

  const int krow = tid >> 4, kc = tid & 15;
  const int vrow = tid >> 3, vc = tid & 7;
  const __bf16* Kbase = Kg + (size_t)h * S_TOT * HDIM;
  const __bf16* Vbase = Vt + (size_t)h * HDIM * S_TOT;

  const int kwoff = krow * 256 + ((kc ^ (krow & 7)) << 4);
  const int vwoff = vrow * 128 + ((vc ^ (vrow & 7)) << 4);

  bf16x8 kreg[4], vreg[4];
  #pragma unroll
  for (int i = 0; i < 4; ++i) {
    kreg[i] = *(const bf16x8*)(Kbase + (size_t)(i*16 + krow) * HDIM + kc * 8);
    vreg[i] = *(const bf16x8*)(Vbase + (size_t)(i*32 + vrow) * S_TOT + vc * 8);
  }

  for (int t = 0; t < S_TOT / 64; ++t) {
    asm volatile("" ::: "memory");
    __builtin_amdgcn_s_barrier();
    asm volatile("" ::: "memory");
    #pragma unroll
    for (int i = 0; i < 4; ++i) {
      *(bf16x8*)(Kc + kwoff + i * 4096) = kreg[i];
      *(bf16x8*)(Vc + vwoff + i * 4096) = vreg[i];
    }
    if (t + 1 < S_TOT / 64) {
      int kv1 = (t + 1) * 64;
      #pragma unroll
      for (int i = 0; i < 4; ++i) {
        kreg[i] = *(const bf16x8*)(Kbase + (size_t)(kv1 + i*16 + krow) * HDIM + kc * 8);
        vreg[i] = *(const bf16x8*)(Vbase + (size_t)(i*32 + vrow) * S_TOT + kv1 + vc * 8);
      }
    }
    asm volatile("s_waitcnt lgkmcnt(0)" ::: "memory");
    __builtin_amdgcn_s_barrier();
    asm volatile("" ::: "memory");

    f32x4 sc[4];
    __builtin_amdgcn_s_setprio(1);
    #pragma unroll
    for (int kb = 0; kb < 4; ++kb) {
      f32x4 s4 = (f32x4){0.f,0.f,0.f,0.f};
      #pragma unroll
      for (int dk = 0; dk < 4; ++dk) {
        bf16x8 kf = *(const bf16x8*)(Kc + (kb*16 + lr) * 256 + (((dk*4 + g) ^ x7) << 4));
        s4 = mfma16(qf[dk], kf, s4);
      }
      sc[kb] = s4;
    }
    __builtin_amdgcn_s_setprio(0);

    float alpha[4];
    #pragma unroll
    for (int r = 0; r < 4; ++r) {
      float mx = fmaxf(fmaxf(sc[0][r], sc[1][r]), fmaxf(sc[2][r], sc[3][r]));
      mx = fmaxf(mx, __shfl_xor(mx, 1));
      mx = fmaxf(mx, __shfl_xor(mx, 2));
      mx = fmaxf(mx, __shfl_xor(mx, 4));
      mx = fmaxf(mx, __shfl_xor(mx, 8));
      float mn = fmaxf(mrow[r], mx);
      float al = __expf(mrow[r] - mn);
      mrow[r] = mn;
      float ps = 0.f;
      #pragma unroll
      for (int kb = 0; kb < 4; ++kb) {
        float p = __expf(sc[kb][r] - mn);
        sc[kb][r] = p;
        ps += p;
      }
      ps += __shfl_xor(ps, 1); ps += __shfl_xor(ps, 2);
      ps += __shfl_xor(ps, 4); ps += __shfl_xor(ps, 8);
      lrow[r] = lrow[r] * al + ps;
      alpha[r] = al;
    }

    #pragma unroll
    for (int kb = 0; kb < 4; ++kb)
      #pragma unroll
      for (int r = 0; r < 4; ++r) {
        int row = g*4 + r;
        *(__bf16*)(Pc + (((row * 128) + (kb*16 + lr) * 2) ^ ((row & 7) << 4))) = (__bf16)sc[kb][r];
      }

    #pragma unroll
    for (int db = 0; db < 8; ++db)
      #pragma unroll
      for (int r = 0; r < 4; ++r) acc[db][r] *= alpha[r];

    bf16x8 ap0 = *(const bf16x8*)(Pc + ((lr * 128 + g * 16) ^ (x7 << 4)));
    bf16x8 ap1 = *(const bf16x8*)(Pc + ((lr * 128 + (4 + g) * 16) ^ (x7 << 4)));
    __builtin_amdgcn_s_setprio(1);
    #pragma unroll
    for (int db = 0; db < 8; ++db) {
      bf16x8 v0 = *(const bf16x8*)(Vc + (db*16 + lr) * 128 + ((g ^ x7) << 4));
      bf16x8 v1 = *(const bf16x8*)(Vc + (db*16 + lr) * 128 + (((4 + g) ^ x7) << 4));
      acc[db] = mfma16(ap0, v0, acc[db]);
      acc[db] = mfma16(ap1, v1, acc[db]);
    }
    __builtin_amdgcn_s_setprio(0);
  }

  float rinv[4];
  #pragma unroll
  for (int r = 0; r < 4; ++r) rinv[r] = 1.f / lrow[r];
  #pragma unroll
  for (int db = 0; db < 8; ++db)
    #pragma unroll
    for (int r = 0; r < 4; ++r) {
      int s = q0 + wave*16 + g*4 + r;
      Og[(size_t)s * DMODEL + h * HDIM + db*16 + lr] = (__bf16)(acc[db][r] * rinv[r]);
    }
}

// ---------------- host ----------------
extern "C" void kernel_launch(void* const* d_in, const int* in_sizes, int n_in,
                              void* d_out, int out_size, void* d_ws, size_t ws_size,
                              hipStream_t stream) {
  const float* x_img   = (const float*)d_in[0];
  const float* x_txt   = (const float*)d_in[1];
  const float* img_cos = (const float*)d_in[2];
  const float* img_sin = (const float*)d_in[3];
  const float* txt_cos = (const float*)d_in[4];
  const float* txt_sin = (const float*)d_in[5];
  const float* Wq  = (const float*)d_in[6];  const float* bq  = (const float*)d_in[7];
  const float* Wk  = (const float*)d_in[8];  const float* bk  = (const float*)d_in[9];
  const float* Wv  = (const float*)d_in[10]; const float* bv  = (const float*)d_in[11];
  const float* Waq = (const float*)d_in[12]; const float* baq = (const float*)d_in[13];
  const float* Wak = (const float*)d_in[14]; const float* bak = (const float*)d_in[15];
  const float* Wav = (const float*)d_in[16]; const float* bav = (const float*)d_in[17];
  const float* Wo  = (const float*)d_in[18]; const float* bo  = (const float*)d_in[19];
  const float* Wao = (const float*)d_in[20]; const float* bao = (const float*)d_in[21];

  __bf16* ws = (__bf16*)d_ws;
  __bf16* Qb  = ws;
  __bf16* Kb  = Qb + SZ_QKV;
  __bf16* Vb  = Kb + SZ_QKV;
  __bf16* Vtb = Vb + SZ_QKV;
  __bf16* AO  = Vtb + SZ_QKV;
  __bf16* XI  = AO + SZ_AO;          // [2304][3072]: rows 0..2047 img, 2048..2303 txt
  __bf16* XT  = XI + SZ_XIMG;

  float* out_img = (float*)d_out;
  float* out_txt = out_img + (size_t)S_IMG * DMODEL;

  cvt_f32_bf16<<<dim3((unsigned)(SZ_XIMG/2048)), 256, 0, stream>>>(x_img, XI, (int)SZ_XIMG);
  cvt_f32_bf16<<<dim3((unsigned)(SZ_XTXT/2048)), 256, 0, stream>>>(x_txt, XT, (int)SZ_XTXT);

  GArgs gq{};
  gq.A = XI;
  gq.W0[0] = Wq;  gq.W0[1] = Wk;  gq.W0[2] = Wv;
  gq.W1[0] = Waq; gq.W1[1] = Wak; gq.W1[2] = Wav;
  gq.b0[0] = bq;  gq.b0[1] = bk;  gq.b0[2] = bv;
  gq.b1[0] = baq; gq.b1[1] = bak; gq.b1[2] = bav;
  gq.O0[0] = Qb;  gq.O0[1] = Kb;  gq.O0[2] = Vb;
  gq.O1[0] = Qb;  gq.O1[1] = Kb;  gq.O1[2] = Vb;
  gemm_all<0><<<dim3(1296), 256, 0, stream>>>(gq);

  rope_kernel<<<dim3(3456, 2), 256, 0, stream>>>(Qb, Kb, img_cos, img_sin, txt_cos, txt_sin);
  transpose_v<<<dim3(36, 24), 128, 0, stream>>>(Vb, Vtb);
  flash_attn<<<dim3(36, 24), 256, 0, stream>>>(Qb, Kb, Vtb, AO);

  GArgs go{};
  go.A = AO;                          // rows 0..255 txt, 256..2303 img
  go.W0[0] = Wo;  go.W1[0] = Wao;
  go.b0[0] = bo;  go.b1[0] = bao;
  go.O0[0] = out_img; go.O1[0] = out_txt;
  gemm_all<1><<<dim3(432), 256, 0, stream>>>(go);

  (void)in_sizes; (void)n_in; (void)out_size; (void)ws_size;
}

// Round 9
// 519.379 us; speedup vs baseline: 1.2505x; 1.2505x over previous
//
#include <hip/hip_runtime.h>
#include <cstdint>
#include <cstddef>

typedef __bf16 bf16x8 __attribute__((ext_vector_type(8)));
typedef float  f32x4  __attribute__((ext_vector_type(4)));

#define S_TXT 256
#define S_IMG 2048
#define S_TOT 2304
#define NHEAD 24
#define HDIM  128
#define DMODEL 3072

static constexpr size_t SZ_QKV  = (size_t)NHEAD * S_TOT * HDIM;
static constexpr size_t SZ_AO   = (size_t)S_TOT * DMODEL;
static constexpr size_t SZ_XIMG = (size_t)S_IMG * DMODEL;
static constexpr size_t SZ_XTXT = (size_t)S_TXT * DMODEL;

__device__ __forceinline__ f32x4 mfma16(bf16x8 a, bf16x8 b, f32x4 c) {
  return __builtin_amdgcn_mfma_f32_16x16x32_bf16(a, b, c, 0, 0, 0);
}

// ---------------- fp32 -> bf16 convert (RNE) ----------------
__global__ __launch_bounds__(256) void cvt_f32_bf16(const float* __restrict__ in,
                                                    __bf16* __restrict__ out, int n) {
  int i = (blockIdx.x * 256 + threadIdx.x) * 8;
  if (i + 8 > n) return;
  f32x4 a = *(const f32x4*)(in + i);
  f32x4 b = *(const f32x4*)(in + i + 4);
  bf16x8 r;
  r[0]=(__bf16)a[0]; r[1]=(__bf16)a[1]; r[2]=(__bf16)a[2]; r[3]=(__bf16)a[3];
  r[4]=(__bf16)b[0]; r[5]=(__bf16)b[1]; r[6]=(__bf16)b[2]; r[7]=(__bf16)b[3];
  *(bf16x8*)(out + i) = r;
}

// ---------------- RoPE in-place; Q additionally pre-scaled by 1/sqrt(HD) ----------------
__global__ __launch_bounds__(256) void rope_kernel(__bf16* __restrict__ Qb, __bf16* __restrict__ Kb,
    const float* __restrict__ icos, const float* __restrict__ isin,
    const float* __restrict__ tcos, const float* __restrict__ tsin) {
  size_t idx = ((size_t)blockIdx.x * 256 + threadIdx.x) * 8;
  __bf16* X; float mult;
  if (blockIdx.y) { X = Kb; mult = 1.0f; }
  else            { X = Qb; mult = 0.08838834764831845f; }
  int d = (int)(idx & 127);
  int s = (int)((idx >> 7) % S_TOT);
  const float *cp, *sp; int ss;
  if (s < S_TXT) { cp = tcos; sp = tsin; ss = s; }
  else           { cp = icos; sp = isin; ss = s - S_TXT; }
  const float* cb = cp + (size_t)ss * HDIM + d;
  const float* sb = sp + (size_t)ss * HDIM + d;
  f32x4 c0 = *(const f32x4*)(cb);
  f32x4 c1 = *(const f32x4*)(cb + 4);
  f32x4 s0 = *(const f32x4*)(sb);
  f32x4 s1 = *(const f32x4*)(sb + 4);
  bf16x8 x = *(const bf16x8*)(X + idx);
  float xf[8];
  #pragma unroll
  for (int j = 0; j < 8; ++j) xf[j] = (float)x[j];
  bf16x8 o;
  o[0] = (__bf16)((xf[0]*c0[0] - xf[1]*s0[0]) * mult);
  o[1] = (__bf16)((xf[1]*c0[1] + xf[0]*s0[1]) * mult);
  o[2] = (__bf16)((xf[2]*c0[2] - xf[3]*s0[2]) * mult);
  o[3] = (__bf16)((xf[3]*c0[3] + xf[2]*s0[3]) * mult);
  o[4] = (__bf16)((xf[4]*c1[0] - xf[5]*s1[0]) * mult);
  o[5] = (__bf16)((xf[5]*c1[1] + xf[4]*s1[1]) * mult);
  o[6] = (__bf16)((xf[6]*c1[2] - xf[7]*s1[2]) * mult);
  o[7] = (__bf16)((xf[7]*c1[3] + xf[6]*s1[3]) * mult);
  *(bf16x8*)(X + idx) = o;
}

// ---------------- V [h][s][d] -> Vt [h][d][s] ----------------
__global__ __launch_bounds__(128) void transpose_v(const __bf16* __restrict__ V,
                                                   __bf16* __restrict__ Vt) {
  int h = blockIdx.y, s0 = blockIdx.x * 64, d = threadIdx.x;
  const __bf16* src = V + ((size_t)h * S_TOT + s0) * HDIM + d;
  __bf16 tmp[64];
  #pragma unroll
  for (int k = 0; k < 64; ++k) tmp[k] = src[(size_t)k * HDIM];
  __bf16* dst = Vt + ((size_t)h * HDIM + d) * S_TOT + s0;
  #pragma unroll
  for (int k = 0; k < 8; ++k) {
    bf16x8 v;
    #pragma unroll
    for (int j = 0; j < 8; ++j) v[j] = tmp[k*8 + j];
    *(bf16x8*)(dst + k*8) = v;
  }
}

// ---------------- fused GEMM, BM=128 x BN=128, BK=64 ----------------
// r9: (256,1) -- NO vgpr cap (r6/r8 lesson: bounds(256,n) caps vgpr at ~256/n
// on this toolchain and caused acc spills). 48KB LDS -> 3 blocks/CU by HW.
// A: LDS dbuf via global_load_lds. B (fp32 W): 1-deep reg prefetch (16 VGPR),
// cvt + swizzled ds_write. Drain moved AFTER COMPUTE so the t+1 loads hide
// under tile-t MFMA work (r4 drained before compute: zero hiding).
struct GArgs {
  const __bf16* A;
  const float* W0[3]; const float* W1[3];
  const float* b0[3]; const float* b1[3];
  void* O0[3]; void* O1[3];
};

#define NT 48   // 3072/64

template<int MODE>
__global__ __launch_bounds__(256, 1) void gemm_all(GArgs ga) {
  const int tid = threadIdx.x;
  const int lane = tid & 63, wave = tid >> 6;
  const int wr = wave >> 1, wc = wave & 1;
  const int g = lane >> 4, lr = lane & 15;
  const int x7 = lr & 7;

  // 1296 = 8 XCD x (9 n-rows x 18 m-tiles), m-fastest (MODE 0)
  //  432 = 8 XCD x (3 n-rows x 18 m-tiles)             (MODE 1)
  const int hw = (int)blockIdx.x;
  const int xcd = hw & 7, idx = hw >> 3;
  const int bx = idx % 18;
  const int nglob = (MODE == 0) ? (xcd * 9 + idx / 18) : (xcd * 3 + idx / 18);
  const int wsel = (MODE == 0) ? nglob / 24 : 0;
  const int ny   = (MODE == 0) ? nglob % 24 : nglob;
  const int m0 = bx * 128;
  const int n0 = ny * 128;
  const bool txt = (MODE == 0) ? (m0 >= S_IMG) : (m0 < S_TXT);
  const float* Wf   = txt ? ga.W1[wsel] : ga.W0[wsel];
  const float* bias = txt ? ga.b1[wsel] : ga.b0[wsel];

  __shared__ __align__(16) __bf16 As[2][128 * 64];   // 2 x 16 KB
  __shared__ __align__(16) __bf16 Bs[128 * 64];      // 16 KB  (48 KB total)

  // A staging: issue i covers rows [i*32,+32); thread -> row i*32 + wave*8 + (l>>3),
  // phys slot l&7; logical chunk (l&7)^(row&7) pre-swizzled on the global side.
  const int sr8 = lane >> 3;
  const int sch = (lane & 7) ^ sr8;
  const __bf16* Ap = ga.A + (size_t)(m0 + wave * 8 + sr8) * DMODEL + sch * 8;

  // W staging: pass p: row p*32 + (tid>>3), fp32 chunk tid&7; swizzled ds_write.
  const int wrow = tid >> 3;
  const int wch  = tid & 7;
  const float* Bp = Wf + (size_t)(n0 + wrow) * DMODEL + wch * 8;
  const int bwoff = wrow * 128 + ((wch ^ (wrow & 7)) << 4);

  f32x4 acc[4][4];
  #pragma unroll
  for (int i = 0; i < 4; ++i)
    #pragma unroll
    for (int j = 0; j < 4; ++j) acc[i][j] = (f32x4){0.f,0.f,0.f,0.f};

  f32x4 pre[4][2];

#define VSEP asm volatile("" ::: "memory")

#define ISSUE_A(kt, buf) { \
    const __bf16* Apk = Ap + (kt) * 64; \
    char* dst = (char*)(&As[(buf)][0]) + wave * 1024; \
    _Pragma("unroll") \
    for (int i_ = 0; i_ < 4; ++i_) \
      __builtin_amdgcn_global_load_lds( \
          (const __attribute__((address_space(1))) void*)(Apk + (size_t)i_ * 32 * DMODEL), \
          (__attribute__((address_space(3))) void*)(dst + i_ * 4096), 16, 0, 0); }

#define ISSUE_B(kt) { \
    const float* Bpk = Bp + (kt) * 64; \
    _Pragma("unroll") \
    for (int p_ = 0; p_ < 4; ++p_) { \
      pre[p_][0] = *(const f32x4*)(Bpk + (size_t)p_ * 32 * DMODEL); \
      pre[p_][1] = *(const f32x4*)(Bpk + (size_t)p_ * 32 * DMODEL + 4); } }

#define WRITE_B() { \
    _Pragma("unroll") \
    for (int p_ = 0; p_ < 4; ++p_) { \
      bf16x8 bw_; \
      _Pragma("unroll") \
      for (int j_ = 0; j_ < 4; ++j_) { \
        bw_[j_]     = (__bf16)pre[p_][0][j_]; \
        bw_[4 + j_] = (__bf16)pre[p_][1][j_]; } \
      *(bf16x8*)((char*)Bs + p_ * 4096 + bwoff) = bw_; } }

#define COMPUTE(buf) { \
    _Pragma("unroll") \
    for (int ks_ = 0; ks_ < 2; ++ks_) { \
      bf16x8 af_[4], bf_[4]; \
      _Pragma("unroll") \
      for (int i_ = 0; i_ < 4; ++i_) \
        af_[i_] = *(const bf16x8*)((char*)(&As[(buf)][0]) + (wr*64 + i_*16 + lr) * 128 + (((ks_*4 + g) ^ x7) << 4)); \
      _Pragma("unroll") \
      for (int j_ = 0; j_ < 4; ++j_) \
        bf_[j_] = *(const bf16x8*)((char*)Bs + (wc*64 + j_*16 + lr) * 128 + (((ks_*4 + g) ^ x7) << 4)); \
      __builtin_amdgcn_s_setprio(1); \
      _Pragma("unroll") \
      for (int i_ = 0; i_ < 4; ++i_) \
        _Pragma("unroll") \
        for (int j_ = 0; j_ < 4; ++j_) \
          acc[i_][j_] = mfma16(af_[i_], bf_[j_], acc[i_][j_]); \
      __builtin_amdgcn_s_setprio(0); } }

  // ---- prologue: tile 0 fully staged ----
  ISSUE_B(0);        VSEP;
  ISSUE_A(0, 0);     VSEP;
  asm volatile("s_waitcnt vmcnt(4)" ::: "memory");    // B[0] regs ready (A[0] may be in flight)
  WRITE_B();
  asm volatile("s_waitcnt vmcnt(0) lgkmcnt(0)" ::: "memory");  // A[0] + Bs resident
  __builtin_amdgcn_s_barrier();
  VSEP;

  // ---- main loop: iters 0..45 as 23 unrolled pairs ----
  // iter t: issue A[t+1],B[t+1]; COMPUTE(t); barrier; drain; WRITE_B; barrier.
  for (int t = 0; t < NT - 2; t += 2) {
    ISSUE_A(t + 1, 1);  VSEP;
    ISSUE_B(t + 1);     VSEP;
    COMPUTE(0);
    __builtin_amdgcn_s_barrier();        // all waves done reading Bs (tile t)
    asm volatile("s_waitcnt vmcnt(0)" ::: "memory");   // A[t+1] in LDS, B[t+1] in regs (hidden under COMPUTE)
    WRITE_B();
    asm volatile("s_waitcnt lgkmcnt(0)" ::: "memory");
    __builtin_amdgcn_s_barrier();
    VSEP;
    ISSUE_A(t + 2, 0);  VSEP;
    ISSUE_B(t + 2);     VSEP;
    COMPUTE(1);
    __builtin_amdgcn_s_barrier();
    asm volatile("s_waitcnt vmcnt(0)" ::: "memory");
    WRITE_B();
    asm volatile("s_waitcnt lgkmcnt(0)" ::: "memory");
    __builtin_amdgcn_s_barrier();
    VSEP;
  }

  // ---- peeled iter 46 (buf0): stage tile 47 ----
  ISSUE_A(NT - 1, 1);  VSEP;
  ISSUE_B(NT - 1);     VSEP;
  COMPUTE(0);
  __builtin_amdgcn_s_barrier();
  asm volatile("s_waitcnt vmcnt(0)" ::: "memory");
  WRITE_B();
  asm volatile("s_waitcnt lgkmcnt(0)" ::: "memory");
  __builtin_amdgcn_s_barrier();
  // ---- peeled iter 47 (buf1) ----
  COMPUTE(1);

#undef VSEP
#undef ISSUE_A
#undef ISSUE_B
#undef WRITE_B
#undef COMPUTE

  float bv[4];
  #pragma unroll
  for (int j = 0; j < 4; ++j) bv[j] = bias[n0 + wc*64 + j*16 + lr];

  if (MODE == 0) {
    __bf16* Qp = (__bf16*)(txt ? ga.O1[wsel] : ga.O0[wsel]);
    const int sbase = txt ? (m0 - S_IMG) : (m0 + S_TXT);
    #pragma unroll
    for (int i = 0; i < 4; ++i)
      #pragma unroll
      for (int j = 0; j < 4; ++j)
        #pragma unroll
        for (int r = 0; r < 4; ++r) {
          int s  = sbase + wr*64 + i*16 + g*4 + r;
          int hd = wc*64 + j*16 + lr;
          Qp[((size_t)ny * S_TOT + s) * HDIM + hd] = (__bf16)(acc[i][j][r] + bv[j]);
        }
  } else {
    float* Cf = (float*)(txt ? ga.O1[0] : ga.O0[0]);
    const int rbase = txt ? m0 : (m0 - S_TXT);
    #pragma unroll
    for (int i = 0; i < 4; ++i)
      #pragma unroll
      for (int j = 0; j < 4; ++j)
        #pragma unroll
        for (int r = 0; r < 4; ++r) {
          int m = rbase + wr*64 + i*16 + g*4 + r;
          int n = n0 + wc*64 + j*16 + lr;
          Cf[(size_t)m * DMODEL + n] = acc[i][j][r] + bv[j];
        }
  }
}

// ---------------- flash attention (r4 structure; bounds (256,2): cap 128 > live ~115) ----------------
__global__ __launch_bounds__(256, 2) void flash_attn(
    const __bf16* __restrict__ Qg, const __bf16* __restrict__ Kg,
    const __bf16* __restrict__ Vt, __bf16* __restrict__ Og)
{
  const int h = blockIdx.y;
  const int q0 = blockIdx.x * 64;
  const int tid = threadIdx.x;
  const int lane = tid & 63, wave = tid >> 6;
  const int g = lane >> 4, lr = lane & 15;
  const int x7 = lr & 7;

  __shared__ __align__(16) __bf16 Kl[64 * 128];    // [kv][d]   256B rows
  __shared__ __align__(16) __bf16 Vl[128 * 64];    // [d][kv]   128B rows
  __shared__ __align__(16) __bf16 Pl[4][16 * 64];  // per-wave [q][kv] 128B rows
  char* Kc = (char*)Kl;
  char* Vc = (char*)Vl;
  char* Pc = (char*)&Pl[wave][0];

  bf16x8 qf[4];
  {
    const __bf16* qp = Qg + ((size_t)h * S_TOT + q0 + wave*16 + lr) * HDIM + g * 8;
    #pragma unroll
    for (int kb = 0; kb < 4; ++kb) qf[kb] = *(const bf16x8*)(qp + kb * 32);
  }

  f32x4 acc[8];
  #pragma unroll
  for (int i = 0; i < 8; ++i) acc[i] = (f32x4){0.f,0.f,0.f,0.f};
  float mrow[4] = {-__builtin_inff(), -__builtin_inff(), -__builtin_inff(), -__builtin_inff()};
  float lrow[4] = {0.f, 0.f, 0.f, 0.f};

  const int krow = tid >> 4, kc = tid & 15;
  const int vrow = tid >> 3, vc = tid & 7;
  const __bf16* Kbase = Kg + (size_t)h * S_TOT * HDIM;
  const __bf16* Vbase = Vt + (size_t)h * HDIM * S_TOT;

  const int kwoff = krow * 256 + ((kc ^ (krow & 7)) << 4);
  const int vwoff = vrow * 128 + ((vc ^ (vrow & 7)) << 4);

  bf16x8 kreg[4], vreg[4];
  #pragma unroll
  for (int i = 0; i < 4; ++i) {
    kreg[i] = *(const bf16x8*)(Kbase + (size_t)(i*16 + krow) * HDIM + kc * 8);
    vreg[i] = *(const bf16x8*)(Vbase + (size_t)(i*32 + vrow) * S_TOT + vc * 8);
  }

  for (int t = 0; t < S_TOT / 64; ++t) {
    asm volatile("" ::: "memory");
    __builtin_amdgcn_s_barrier();
    asm volatile("" ::: "memory");
    #pragma unroll
    for (int i = 0; i < 4; ++i) {
      *(bf16x8*)(Kc + kwoff + i * 4096) = kreg[i];
      *(bf16x8*)(Vc + vwoff + i * 4096) = vreg[i];
    }
    if (t + 1 < S_TOT / 64) {
      int kv1 = (t + 1) * 64;
      #pragma unroll
      for (int i = 0; i < 4; ++i) {
        kreg[i] = *(const bf16x8*)(Kbase + (size_t)(kv1 + i*16 + krow) * HDIM + kc * 8);
        vreg[i] = *(const bf16x8*)(Vbase + (size_t)(i*32 + vrow) * S_TOT + kv1 + vc * 8);
      }
    }
    asm volatile("s_waitcnt lgkmcnt(0)" ::: "memory");
    __builtin_amdgcn_s_barrier();
    asm volatile("" ::: "memory");

    f32x4 sc[4];
    __builtin_amdgcn_s_setprio(1);
    #pragma unroll
    for (int kb = 0; kb < 4; ++kb) {
      f32x4 s4 = (f32x4){0.f,0.f,0.f,0.f};
      #pragma unroll
      for (int dk = 0; dk < 4; ++dk) {
        bf16x8 kf = *(const bf16x8*)(Kc + (kb*16 + lr) * 256 + (((dk*4 + g) ^ x7) << 4));
        s4 = mfma16(qf[dk], kf, s4);
      }
      sc[kb] = s4;
    }
    __builtin_amdgcn_s_setprio(0);

    float alpha[4];
    #pragma unroll
    for (int r = 0; r < 4; ++r) {
      float mx = fmaxf(fmaxf(sc[0][r], sc[1][r]), fmaxf(sc[2][r], sc[3][r]));
      mx = fmaxf(mx, __shfl_xor(mx, 1));
      mx = fmaxf(mx, __shfl_xor(mx, 2));
      mx = fmaxf(mx, __shfl_xor(mx, 4));
      mx = fmaxf(mx, __shfl_xor(mx, 8));
      float mn = fmaxf(mrow[r], mx);
      float al = __expf(mrow[r] - mn);
      mrow[r] = mn;
      float ps = 0.f;
      #pragma unroll
      for (int kb = 0; kb < 4; ++kb) {
        float p = __expf(sc[kb][r] - mn);
        sc[kb][r] = p;
        ps += p;
      }
      ps += __shfl_xor(ps, 1); ps += __shfl_xor(ps, 2);
      ps += __shfl_xor(ps, 4); ps += __shfl_xor(ps, 8);
      lrow[r] = lrow[r] * al + ps;
      alpha[r] = al;
    }

    #pragma unroll
    for (int kb = 0; kb < 4; ++kb)
      #pragma unroll
      for (int r = 0; r < 4; ++r) {
        int row = g*4 + r;
        *(__bf16*)(Pc + (((row * 128) + (kb*16 + lr) * 2) ^ ((row & 7) << 4))) = (__bf16)sc[kb][r];
      }

    #pragma unroll
    for (int db = 0; db < 8; ++db)
      #pragma unroll
      for (int r = 0; r < 4; ++r) acc[db][r] *= alpha[r];

    bf16x8 ap0 = *(const bf16x8*)(Pc + ((lr * 128 + g * 16) ^ (x7 << 4)));
    bf16x8 ap1 = *(const bf16x8*)(Pc + ((lr * 128 + (4 + g) * 16) ^ (x7 << 4)));
    __builtin_amdgcn_s_setprio(1);
    #pragma unroll
    for (int db = 0; db < 8; ++db) {
      bf16x8 v0 = *(const bf16x8*)(Vc + (db*16 + lr) * 128 + ((g ^ x7) << 4));
      bf16x8 v1 = *(const bf16x8*)(Vc + (db*16 + lr) * 128 + (((4 + g) ^ x7) << 4));
      acc[db] = mfma16(ap0, v0, acc[db]);
      acc[db] = mfma16(ap1, v1, acc[db]);
    }
    __builtin_amdgcn_s_setprio(0);
  }

  float rinv[4];
  #pragma unroll
  for (int r = 0; r < 4; ++r) rinv[r] = 1.f / lrow[r];
  #pragma unroll
  for (int db = 0; db < 8; ++db)
    #pragma unroll
    for (int r = 0; r < 4; ++r) {
      int s = q0 + wave*16 + g*4 + r;
      Og[(size_t)s * DMODEL + h * HDIM + db*16 + lr] = (__bf16)(acc[db][r] * rinv[r]);
    }
}

// ---------------- host ----------------
extern "C" void kernel_launch(void* const* d_in, const int* in_sizes, int n_in,
                              void* d_out, int out_size, void* d_ws, size_t ws_size,
                              hipStream_t stream) {
  const float* x_img   = (const float*)d_in[0];
  const float* x_txt   = (const float*)d_in[1];
  const float* img_cos = (const float*)d_in[2];
  const float* img_sin = (const float*)d_in[3];
  const float* txt_cos = (const float*)d_in[4];
  const float* txt_sin = (const float*)d_in[5];
  const float* Wq  = (const float*)d_in[6];  const float* bq  = (const float*)d_in[7];
  const float* Wk  = (const float*)d_in[8];  const float* bk  = (const float*)d_in[9];
  const float* Wv  = (const float*)d_in[10]; const float* bv  = (const float*)d_in[11];
  const float* Waq = (const float*)d_in[12]; const float* baq = (const float*)d_in[13];
  const float* Wak = (const float*)d_in[14]; const float* bak = (const float*)d_in[15];
  const float* Wav = (const float*)d_in[16]; const float* bav = (const float*)d_in[17];
  const float* Wo  = (const float*)d_in[18]; const float* bo  = (const float*)d_in[19];
  const float* Wao = (const float*)d_in[20]; const float* bao = (const float*)d_in[21];

  __bf16* ws = (__bf16*)d_ws;
  __bf16* Qb  = ws;
  __bf16* Kb  = Qb + SZ_QKV;
  __bf16* Vb  = Kb + SZ_QKV;
  __bf16* Vtb = Vb + SZ_QKV;
  __bf16* AO  = Vtb + SZ_QKV;
  __bf16* XI  = AO + SZ_AO;          // [2304][3072]: rows 0..2047 img, 2048..2303 txt
  __bf16* XT  = XI + SZ_XIMG;

  float* out_img = (float*)d_out;
  float* out_txt = out_img + (size_t)S_IMG * DMODEL;

  cvt_f32_bf16<<<dim3((unsigned)(SZ_XIMG/2048)), 256, 0, stream>>>(x_img, XI, (int)SZ_XIMG);
  cvt_f32_bf16<<<dim3((unsigned)(SZ_XTXT/2048)), 256, 0, stream>>>(x_txt, XT, (int)SZ_XTXT);

  GArgs gq{};
  gq.A = XI;
  gq.W0[0] = Wq;  gq.W0[1] = Wk;  gq.W0[2] = Wv;
  gq.W1[0] = Waq; gq.W1[1] = Wak; gq.W1[2] = Wav;
  gq.b0[0] = bq;  gq.b0[1] = bk;  gq.b0[2] = bv;
  gq.b1[0] = baq; gq.b1[1] = bak; gq.b1[2] = bav;
  gq.O0[0] = Qb;  gq.O0[1] = Kb;  gq.O0[2] = Vb;
  gq.O1[0] = Qb;  gq.O1[1] = Kb;  gq.O1[2] = Vb;
  gemm_all<0><<<dim3(1296), 256, 0, stream>>>(gq);

  rope_kernel<<<dim3(3456, 2), 256, 0, stream>>>(Qb, Kb, img_cos, img_sin, txt_cos, txt_sin);
  transpose_v<<<dim3(36, 24), 128, 0, stream>>>(Vb, Vtb);
  flash_attn<<<dim3(36, 24), 256, 0, stream>>>(Qb, Kb, Vtb, AO);

  GArgs go{};
  go.A = AO;                          // rows 0..255 txt, 256..2303 img
  go.W0[0] = Wo;  go.W1[0] = Wao;
  go.b0[0] = bo;  go.b1[0] = bao;
  go.O0[0] = out_img; go.O1[0] = out_txt;
  gemm_all<1><<<dim3(432), 256, 0, stream>>>(go);

  (void)in_sizes; (void)n_in; (void)out_size; (void)ws_size;
}